// Round 1
// baseline (720.962 us; speedup 1.0000x reference)
//
#include <hip/hip_runtime.h>
#include <math.h>

#define NBATCH 8
#define HH 512
#define WW 512
#define NF 24
#define NB 31
#define TILE 32
#define SPT 36   // TILE + 4 (scaled_phi halo for 5x5 second conv)
#define UT 40    // TILE + 8 (u halo: 2 for sp halo + 2 for first conv)

__global__ void zero_ws_kernel(float* ws) { if (threadIdx.x == 0) ws[0] = 0.f; }

// sum over all pixels of clip(u) * (#pool windows covering pixel)/9
// == sum(u_sigma);  M = sum/(B*H*W) + 0.001 computed in main kernel.
__global__ __launch_bounds__(256) void reduce_m_kernel(const float* __restrict__ u,
                                                       float* __restrict__ ws) {
    const int N = NBATCH * HH * WW;
    int stride = gridDim.x * blockDim.x;
    float s = 0.f;
    for (int i = blockIdx.x * blockDim.x + threadIdx.x; i < N; i += stride) {
        int x = i & (WW - 1);
        int y = (i >> 9) & (HH - 1);
        float v = fminf(fmaxf(u[i], 1e-4f), 1.0f);
        float wy = (y == 0 || y == HH - 1) ? 2.f : 3.f;
        float wx = (x == 0 || x == WW - 1) ? 2.f : 3.f;
        s += v * (wy * wx);
    }
#pragma unroll
    for (int off = 32; off > 0; off >>= 1) s += __shfl_down(s, off, 64);
    if ((threadIdx.x & 63) == 0) atomicAdd(ws, s);
}

__global__ __launch_bounds__(256) void tnrd_kernel(
    const float* __restrict__ u, const float* __restrict__ f,
    const float* __restrict__ filt, const float* __restrict__ mu,
    const float* __restrict__ wts, const float* __restrict__ lamp,
    const float* __restrict__ ws, float* __restrict__ out)
{
    __shared__ float su[UT][UT];      // clipped u tile, 0 outside image
    __shared__ float usig[SPT][SPT];  // (u_sigma/M), 0 outside image
    __shared__ float sp[SPT][SPT];    // scaled_phi for current filter
    __shared__ float sfilt[NF][25];
    __shared__ float smu[NF][NB];
    __shared__ float swt[NF][NB];

    const int tid = threadIdx.x;
    const int bz = blockIdx.z;
    const int oy0 = blockIdx.y * TILE;
    const int ox0 = blockIdx.x * TILE;
    const float* ub = u + bz * HH * WW;

    for (int i = tid; i < NF * 25; i += 256) (&sfilt[0][0])[i] = filt[i];
    for (int i = tid; i < NF * NB; i += 256) {
        (&smu[0][0])[i] = mu[i];
        (&swt[0][0])[i] = wts[i];
    }

    // stage u tile (halo 4), clipped; zero outside image (matches conv zero-pad)
    for (int i = tid; i < UT * UT; i += 256) {
        int uy = i / UT, ux = i - uy * UT;
        int gy = oy0 - 4 + uy, gx = ox0 - 4 + ux;
        float v = 0.f;
        if ((unsigned)gy < (unsigned)HH && (unsigned)gx < (unsigned)WW)
            v = fminf(fmaxf(ub[gy * WW + gx], 1e-4f), 1.0f);
        su[uy][ux] = v;
    }
    __syncthreads();

    const float Mv = ws[0] * (1.0f / (9.0f * NBATCH * HH * WW)) + 0.001f;
    const float invM = 1.0f / Mv;

    // u_sigma/M on the sp grid; MUST be zero outside the image because the
    // second conv zero-pads scaled_phi.
    for (int i = tid; i < SPT * SPT; i += 256) {
        int py = i / SPT, px = i - py * SPT;
        int gy = oy0 - 2 + py, gx = ox0 - 2 + px;
        float s = 0.f;
        if ((unsigned)gy < (unsigned)HH && (unsigned)gx < (unsigned)WW) {
#pragma unroll
            for (int dy = 0; dy < 3; ++dy)
#pragma unroll
                for (int dx = 0; dx < 3; ++dx)
                    s += su[py + 1 + dy][px + 1 + dx];
            s *= (1.f / 9.f) * invM;
        }
        usig[py][px] = s;
    }
    __syncthreads();

    const int ty = tid >> 5, tx = tid & 31;
    float dif[4] = {0.f, 0.f, 0.f, 0.f};

    for (int c = 0; c < NF; ++c) {
        // scaled_phi for filter c over the 36x36 region
        for (int i = tid; i < SPT * SPT; i += 256) {
            int py = i / SPT, px = i - py * SPT;
            float x = 0.f;
#pragma unroll
            for (int dy = 0; dy < 5; ++dy)
#pragma unroll
                for (int dx = 0; dx < 5; ++dx)
                    x = fmaf(sfilt[c][dy * 5 + dx], su[py + dy][px + dx], x);
            float phi = 0.f;
#pragma unroll
            for (int j = 0; j < NB; ++j) {
                float d = x - smu[c][j];
                phi = fmaf(swt[c][j], __expf(-2.0f * d * d), phi);
            }
            sp[py][px] = usig[py][px] * phi;
        }
        __syncthreads();
        // accumulate diffusion: correlation with flipped filter
#pragma unroll
        for (int r = 0; r < 4; ++r) {
            int orow = ty + r * 8;
            float acc = dif[r];
#pragma unroll
            for (int dy = 0; dy < 5; ++dy)
#pragma unroll
                for (int dx = 0; dx < 5; ++dx)
                    acc = fmaf(sfilt[c][(4 - dy) * 5 + (4 - dx)],
                               sp[orow + dy][tx + dx], acc);
            dif[r] = acc;
        }
        __syncthreads();
    }

    const float lam = lamp[0];
    const float* fb = f + bz * HH * WW;
    float* ob = out + bz * HH * WW;
#pragma unroll
    for (int r = 0; r < 4; ++r) {
        int orow = ty + r * 8;
        int gy = oy0 + orow, gx = ox0 + tx;
        float uv = su[orow + 4][tx + 4];
        float fv = fminf(fmaxf(fb[gy * WW + gx], 1e-4f), 1.0f);
        float reac = lam * (uv - fv) / (uv + 0.05f);
        float o = uv - dif[r] - reac;
        ob[gy * WW + gx] = fminf(fmaxf(o, 0.f), 1.f);
    }
}

extern "C" void kernel_launch(void* const* d_in, const int* in_sizes, int n_in,
                              void* d_out, int out_size, void* d_ws, size_t ws_size,
                              hipStream_t stream) {
    const float* u = (const float*)d_in[0];
    const float* f = (const float*)d_in[1];
    const float* filt = (const float*)d_in[2];
    const float* mu = (const float*)d_in[3];
    const float* wts = (const float*)d_in[4];
    const float* lam = (const float*)d_in[5];
    float* ws = (float*)d_ws;
    float* out = (float*)d_out;

    zero_ws_kernel<<<1, 64, 0, stream>>>(ws);
    reduce_m_kernel<<<1024, 256, 0, stream>>>(u, ws);
    dim3 grid(WW / TILE, HH / TILE, NBATCH);
    tnrd_kernel<<<grid, 256, 0, stream>>>(u, f, filt, mu, wts, lam, ws, out);
}

// Round 2
// 433.343 us; speedup vs baseline: 1.6637x; 1.6637x over previous
//
#include <hip/hip_runtime.h>
#include <math.h>

#define NBATCH 8
#define HH 512
#define WW 512
#define NF 24
#define NB 31
#define TILE 32
#define SPT 36   // TILE + 4 (scaled_phi halo for 5x5 second conv)
#define UT 40    // TILE + 8 (u halo: 2 for sp halo + 2 for first conv)
#define LOG2E 1.4426950408889634f

__global__ void zero_ws_kernel(float* ws) { if (threadIdx.x == 0) ws[0] = 0.f; }

// sum over all pixels of clip(u) * (#pool windows covering pixel)/9 == sum(u_sigma)
__global__ __launch_bounds__(256) void reduce_m_kernel(const float* __restrict__ u,
                                                       float* __restrict__ ws) {
    const int N = NBATCH * HH * WW;
    int stride = gridDim.x * blockDim.x;
    float s = 0.f;
    for (int i = blockIdx.x * blockDim.x + threadIdx.x; i < N; i += stride) {
        int x = i & (WW - 1);
        int y = (i >> 9) & (HH - 1);
        float v = fminf(fmaxf(u[i], 1e-4f), 1.0f);
        float wy = (y == 0 || y == HH - 1) ? 2.f : 3.f;
        float wx = (x == 0 || x == WW - 1) ? 2.f : 3.f;
        s += v * (wy * wx);
    }
#pragma unroll
    for (int off = 32; off > 0; off >>= 1) s += __shfl_down(s, off, 64);
    if ((threadIdx.x & 63) == 0) atomicAdd(ws, s);
}

__global__ __launch_bounds__(256) void tnrd_kernel(
    const float* __restrict__ u, const float* __restrict__ f,
    const float* __restrict__ filt, const float* __restrict__ mu,
    const float* __restrict__ wts, const float* __restrict__ lamp,
    const float* __restrict__ ws, float* __restrict__ out)
{
    __shared__ float su[UT][UT];      // clipped u tile, 0 outside image
    __shared__ float usig[SPT][SPT];  // (u_sigma/M), 0 outside image
    __shared__ float sp[SPT][SPT];    // scaled_phi for current filter

    const int tid = threadIdx.x;
    const int bz = blockIdx.z;
    const int oy0 = blockIdx.y * TILE;
    const int ox0 = blockIdx.x * TILE;
    const float* ub = u + bz * HH * WW;

    // stage u tile (halo 4), clipped; zero outside image (matches conv zero-pad)
    for (int i = tid; i < UT * UT; i += 256) {
        int uy = i / UT, ux = i - uy * UT;
        int gy = oy0 - 4 + uy, gx = ox0 - 4 + ux;
        float v = 0.f;
        if ((unsigned)gy < (unsigned)HH && (unsigned)gx < (unsigned)WW)
            v = fminf(fmaxf(ub[gy * WW + gx], 1e-4f), 1.0f);
        su[uy][ux] = v;
    }
    __syncthreads();

    const float Mv = ws[0] * (1.0f / (9.0f * NBATCH * HH * WW)) + 0.001f;
    const float invM = 1.0f / Mv;

    // u_sigma/M on the sp grid; zero outside the image (second conv zero-pads)
    for (int i = tid; i < SPT * SPT; i += 256) {
        int py = i / SPT, px = i - py * SPT;
        int gy = oy0 - 2 + py, gx = ox0 - 2 + px;
        float s = 0.f;
        if ((unsigned)gy < (unsigned)HH && (unsigned)gx < (unsigned)WW) {
#pragma unroll
            for (int dy = 0; dy < 3; ++dy)
#pragma unroll
                for (int dx = 0; dx < 3; ++dx)
                    s += su[py + 1 + dy][px + 1 + dx];
            s *= (1.f / 9.f) * invM;
        }
        usig[py][px] = s;
    }

    // diffusion thread mapping: one 1x4 quad of outputs per thread
    const int orow = tid >> 3;           // 0..31
    const int px0o = (tid & 7) * 4;      // 0,4,...,28
    float dif[4] = {0.f, 0.f, 0.f, 0.f};

    __syncthreads();

    for (int c = 0; c < NF; ++c) {
        const float* fc = filt + c * 25;   // uniform -> s_load
        const float* wc = wts + c * NB;    // uniform -> s_load
        const float mu0 = mu[c * NB];
        const float dlt = mu[c * NB + 1] - mu0;   // linspace spacing
        // E_j = exp(-2 (x-mu_j)^2):  E_{j+1} = E_j * r,  r *= q
        const float nc = -2.0f * LOG2E;                       // exp2 scale
        const float a4 = 4.0f * LOG2E * dlt;
        const float bb = -2.0f * LOG2E * dlt * dlt;
        const float qq = exp2f(-4.0f * LOG2E * dlt * dlt);

        // scaled_phi for filter c over 36x36, one 1x4 quad per task
        for (int i = tid; i < (SPT / 4) * SPT; i += 256) {  // 324 tasks
            int py = i / (SPT / 4);
            int px0 = (i - py * (SPT / 4)) * 4;
            float x0 = 0.f, x1 = 0.f, x2 = 0.f, x3 = 0.f;
#pragma unroll
            for (int dy = 0; dy < 5; ++dy) {
                float4 va = *(const float4*)&su[py + dy][px0];
                float4 vb = *(const float4*)&su[py + dy][px0 + 4];
                float r[8] = {va.x, va.y, va.z, va.w, vb.x, vb.y, vb.z, vb.w};
#pragma unroll
                for (int dx = 0; dx < 5; ++dx) {
                    float w = fc[dy * 5 + dx];
                    x0 = fmaf(w, r[dx], x0);
                    x1 = fmaf(w, r[dx + 1], x1);
                    x2 = fmaf(w, r[dx + 2], x2);
                    x3 = fmaf(w, r[dx + 3], x3);
                }
            }
            float xx[4] = {x0, x1, x2, x3};
            float4 us = *(const float4*)&usig[py][px0];
            float uu[4] = {us.x, us.y, us.z, us.w};
            float ph[4];
#pragma unroll
            for (int k = 0; k < 4; ++k) {
                float t = xx[k] - mu0;
                float e = exp2f(t * t * nc);
                float r = exp2f(fmaf(a4, t, bb));
                float phi = 0.f;
#pragma unroll
                for (int j = 0; j < NB; ++j) {
                    phi = fmaf(wc[j], e, phi);
                    e *= r;
                    r *= qq;
                }
                ph[k] = phi * uu[k];
            }
            *(float4*)&sp[py][px0] = make_float4(ph[0], ph[1], ph[2], ph[3]);
        }
        __syncthreads();

        // accumulate diffusion: correlation of sp with flipped filter
        {
            float a0 = dif[0], a1 = dif[1], a2 = dif[2], a3 = dif[3];
#pragma unroll
            for (int dy = 0; dy < 5; ++dy) {
                float4 va = *(const float4*)&sp[orow + dy][px0o];
                float4 vb = *(const float4*)&sp[orow + dy][px0o + 4];
                float r[8] = {va.x, va.y, va.z, va.w, vb.x, vb.y, vb.z, vb.w};
#pragma unroll
                for (int dx = 0; dx < 5; ++dx) {
                    float w = fc[(4 - dy) * 5 + (4 - dx)];
                    a0 = fmaf(w, r[dx], a0);
                    a1 = fmaf(w, r[dx + 1], a1);
                    a2 = fmaf(w, r[dx + 2], a2);
                    a3 = fmaf(w, r[dx + 3], a3);
                }
            }
            dif[0] = a0; dif[1] = a1; dif[2] = a2; dif[3] = a3;
        }
        __syncthreads();
    }

    const float lam = lamp[0];
    const float* fb = f + bz * HH * WW;
    float* ob = out + bz * HH * WW;
    {
        int gy = oy0 + orow, gx = ox0 + px0o;
        float o[4];
#pragma unroll
        for (int k = 0; k < 4; ++k) {
            float uv = su[orow + 4][px0o + k + 4];
            float fv = fminf(fmaxf(fb[gy * WW + gx + k], 1e-4f), 1.0f);
            float reac = lam * (uv - fv) / (uv + 0.05f);
            o[k] = fminf(fmaxf(uv - dif[k] - reac, 0.f), 1.f);
        }
        *(float4*)&ob[gy * WW + gx] = make_float4(o[0], o[1], o[2], o[3]);
    }
}

extern "C" void kernel_launch(void* const* d_in, const int* in_sizes, int n_in,
                              void* d_out, int out_size, void* d_ws, size_t ws_size,
                              hipStream_t stream) {
    const float* u = (const float*)d_in[0];
    const float* f = (const float*)d_in[1];
    const float* filt = (const float*)d_in[2];
    const float* mu = (const float*)d_in[3];
    const float* wts = (const float*)d_in[4];
    const float* lam = (const float*)d_in[5];
    float* ws = (float*)d_ws;
    float* out = (float*)d_out;

    zero_ws_kernel<<<1, 64, 0, stream>>>(ws);
    reduce_m_kernel<<<1024, 256, 0, stream>>>(u, ws);
    dim3 grid(WW / TILE, HH / TILE, NBATCH);
    tnrd_kernel<<<grid, 256, 0, stream>>>(u, f, filt, mu, wts, lam, ws, out);
}

// Round 3
// 319.955 us; speedup vs baseline: 2.2533x; 1.3544x over previous
//
#include <hip/hip_runtime.h>
#include <math.h>

#define NBATCH 8
#define HH 512
#define WW 512
#define NF 24
#define NB 31
#define TILE 32
#define SPT 36   // TILE + 4 (scaled_phi halo for 5x5 second conv)
#define UT 40    // TILE + 8 (u halo)
#define SU_S 44  // padded LDS row stride (floats): 12*row mod 32 spreads banks
#define SP_S 44
#define LUTN 256
#define WS_LO 8
#define WS_SC 40
#define WS_LUT 72

__global__ void zero_ws_kernel(float* ws) { if (threadIdx.x == 0) ws[0] = 0.f; }

// sum over all pixels of clip(u) * (#pool windows covering pixel)/9 == sum(u_sigma)
__global__ __launch_bounds__(256) void reduce_m_kernel(const float* __restrict__ u,
                                                       float* __restrict__ ws) {
    const int N = NBATCH * HH * WW;
    int stride = gridDim.x * blockDim.x;
    float s = 0.f;
    for (int i = blockIdx.x * blockDim.x + threadIdx.x; i < N; i += stride) {
        int x = i & (WW - 1);
        int y = (i >> 9) & (HH - 1);
        float v = fminf(fmaxf(u[i], 1e-4f), 1.0f);
        float wy = (y == 0 || y == HH - 1) ? 2.f : 3.f;
        float wx = (x == 0 || x == WW - 1) ? 2.f : 3.f;
        s += v * (wy * wx);
    }
#pragma unroll
    for (int off = 32; off > 0; off >>= 1) s += __shfl_down(s, off, 64);
    if ((threadIdx.x & 63) == 0) atomicAdd(ws, s);
}

// Per-filter phi LUT over the exact attainable x-range.
__global__ __launch_bounds__(256) void lut_kernel(const float* __restrict__ filt,
                                                  const float* __restrict__ mu,
                                                  const float* __restrict__ wts,
                                                  float* __restrict__ ws) {
    const int c = blockIdx.x;
    const int t = threadIdx.x;
    float lo = 0.f, hi = 0.f;
    for (int i = 0; i < 25; ++i) {
        float k = filt[c * 25 + i];
        lo += fminf(k, k * 1e-4f);
        hi += fmaxf(k, k * 1e-4f);
    }
    float rng = fmaxf(hi - lo, 1e-9f);
    float x = lo + (float)t * (rng * (1.f / 255.f));
    float phi = 0.f;
    for (int j = 0; j < NB; ++j) {
        float d = x - mu[c * NB + j];
        phi += wts[c * NB + j] * expf(-2.f * d * d);
    }
    ws[WS_LUT + c * LUTN + t] = phi;
    if (t == 0) { ws[WS_LO + c] = lo; ws[WS_SC + c] = 255.f / rng; }
}

__device__ __forceinline__ float4 usig_task(int i, const float (*su)[SU_S],
                                            int oy0, int ox0, float inv9M) {
    int py = i / 9;
    int px0 = (i - py * 9) * 4;
    float s0 = 0.f, s1 = 0.f, s2 = 0.f, s3 = 0.f;
#pragma unroll
    for (int dy = 0; dy < 3; ++dy) {
        const float* row = &su[py + 1 + dy][0];
        float4 a = *(const float4*)&row[px0];
        float4 b = *(const float4*)&row[px0 + 4];
        s0 += a.y + a.z + a.w;
        s1 += a.z + a.w + b.x;
        s2 += a.w + b.x + b.y;
        s3 += b.x + b.y + b.z;
    }
    int gy = oy0 - 2 + py;
    int gx = ox0 - 2 + px0;
    bool ry = (unsigned)gy < (unsigned)HH;
    float4 r;
    r.x = (ry && (unsigned)(gx + 0) < (unsigned)WW) ? s0 * inv9M : 0.f;
    r.y = (ry && (unsigned)(gx + 1) < (unsigned)WW) ? s1 * inv9M : 0.f;
    r.z = (ry && (unsigned)(gx + 2) < (unsigned)WW) ? s2 * inv9M : 0.f;
    r.w = (ry && (unsigned)(gx + 3) < (unsigned)WW) ? s3 * inv9M : 0.f;
    return r;
}

__device__ __forceinline__ void sp_task(int i, float4 uu,
                                        const float (*su)[SU_S], float (*sp)[SP_S],
                                        const float* __restrict__ slc,
                                        float scc, float offc,
                                        const float* __restrict__ fc) {
    int py = i / 9;
    int px0 = (i - py * 9) * 4;
    float x0 = 0.f, x1 = 0.f, x2 = 0.f, x3 = 0.f;
#pragma unroll
    for (int dy = 0; dy < 5; ++dy) {
        float4 va = *(const float4*)&su[py + dy][px0];
        float4 vb = *(const float4*)&su[py + dy][px0 + 4];
        float r[8] = {va.x, va.y, va.z, va.w, vb.x, vb.y, vb.z, vb.w};
#pragma unroll
        for (int dx = 0; dx < 5; ++dx) {
            float w = fc[dy * 5 + dx];
            x0 = fmaf(w, r[dx], x0);
            x1 = fmaf(w, r[dx + 1], x1);
            x2 = fmaf(w, r[dx + 2], x2);
            x3 = fmaf(w, r[dx + 3], x3);
        }
    }
    float xx[4] = {x0, x1, x2, x3};
    float uu4[4] = {uu.x, uu.y, uu.z, uu.w};
    float ph[4];
#pragma unroll
    for (int k = 0; k < 4; ++k) {
        float t = fmaf(xx[k], scc, offc);
        t = fminf(fmaxf(t, 0.f), 254.999f);
        int i0 = (int)t;
        float fr = t - (float)i0;
        float v0 = slc[i0];
        float v1 = slc[i0 + 1];
        ph[k] = fmaf(fr, v1 - v0, v0) * uu4[k];
    }
    *(float4*)&sp[py][px0] = make_float4(ph[0], ph[1], ph[2], ph[3]);
}

template <bool WSLUT>
__global__ __launch_bounds__(256) void tnrd_kernel(
    const float* __restrict__ u, const float* __restrict__ f,
    const float* __restrict__ filt, const float* __restrict__ mu,
    const float* __restrict__ wts, const float* __restrict__ lamp,
    const float* __restrict__ ws, float* __restrict__ out)
{
    __shared__ float su[UT][SU_S];
    __shared__ float sp[SPT][SP_S];
    __shared__ float slut[NF][LUTN];
    __shared__ float slo[NF];
    __shared__ float ssc[NF];

    const int tid = threadIdx.x;
    const int bz = blockIdx.z;
    const int oy0 = blockIdx.y * TILE;
    const int ox0 = blockIdx.x * TILE;
    const float* ub = u + bz * HH * WW;

    // stage clipped u tile (halo 4); zero outside image
    for (int i = tid; i < UT * UT; i += 256) {
        int uy = i / UT, ux = i - uy * UT;
        int gy = oy0 - 4 + uy, gx = ox0 - 4 + ux;
        float v = 0.f;
        if ((unsigned)gy < (unsigned)HH && (unsigned)gx < (unsigned)WW)
            v = fminf(fmaxf(ub[gy * WW + gx], 1e-4f), 1.0f);
        su[uy][ux] = v;
    }

    // fill per-filter LUTs
    if (WSLUT) {
        const float4* lsrc = (const float4*)(ws + WS_LUT);
        float4* ldst = (float4*)&slut[0][0];
        for (int i = tid; i < NF * LUTN / 4; i += 256) ldst[i] = lsrc[i];
        if (tid < NF) { slo[tid] = ws[WS_LO + tid]; ssc[tid] = ws[WS_SC + tid]; }
    } else {
        for (int k = 0; k < NF; ++k) {
            float lo = 0.f, hi = 0.f;
            for (int i = 0; i < 25; ++i) {
                float kv = filt[k * 25 + i];
                lo += fminf(kv, kv * 1e-4f);
                hi += fmaxf(kv, kv * 1e-4f);
            }
            float rng = fmaxf(hi - lo, 1e-9f);
            float x = lo + (float)tid * (rng * (1.f / 255.f));
            float phi = 0.f;
            for (int j = 0; j < NB; ++j) {
                float d = x - mu[k * NB + j];
                phi += wts[k * NB + j] * __expf(-2.f * d * d);
            }
            slut[k][tid] = phi;
            if (tid == 0) { slo[k] = lo; ssc[k] = 255.f / rng; }
        }
    }
    __syncthreads();

    const float Mv = ws[0] * (1.0f / (9.0f * NBATCH * HH * WW)) + 0.001f;
    const float inv9M = (1.f / 9.f) / Mv;

    // u_sigma/M in registers, same task mapping as sp loop (324 quad-tasks)
    float4 ug0 = usig_task(tid, su, oy0, ox0, inv9M);
    float4 ug1 = make_float4(0.f, 0.f, 0.f, 0.f);
    if (tid < 324 - 256) ug1 = usig_task(tid + 256, su, oy0, ox0, inv9M);

    const int orow = tid >> 3;
    const int px0o = (tid & 7) * 4;
    float dif[4] = {0.f, 0.f, 0.f, 0.f};

    for (int c = 0; c < NF; ++c) {
        const float* fc = filt + c * 25;
        const float* slc = &slut[c][0];
        float lo = slo[c], scc = ssc[c];
        float offc = -lo * scc;

        sp_task(tid, ug0, su, sp, slc, scc, offc, fc);
        if (tid < 324 - 256) sp_task(tid + 256, ug1, su, sp, slc, scc, offc, fc);
        __syncthreads();

        // diffusion: correlation of sp with flipped filter
        {
            float a0 = dif[0], a1 = dif[1], a2 = dif[2], a3 = dif[3];
#pragma unroll
            for (int dy = 0; dy < 5; ++dy) {
                float4 va = *(const float4*)&sp[orow + dy][px0o];
                float4 vb = *(const float4*)&sp[orow + dy][px0o + 4];
                float r[8] = {va.x, va.y, va.z, va.w, vb.x, vb.y, vb.z, vb.w};
#pragma unroll
                for (int dx = 0; dx < 5; ++dx) {
                    float w = fc[(4 - dy) * 5 + (4 - dx)];
                    a0 = fmaf(w, r[dx], a0);
                    a1 = fmaf(w, r[dx + 1], a1);
                    a2 = fmaf(w, r[dx + 2], a2);
                    a3 = fmaf(w, r[dx + 3], a3);
                }
            }
            dif[0] = a0; dif[1] = a1; dif[2] = a2; dif[3] = a3;
        }
        __syncthreads();
    }

    const float lam = lamp[0];
    const float* fb = f + bz * HH * WW;
    float* ob = out + bz * HH * WW;
    {
        int gy = oy0 + orow, gx = ox0 + px0o;
        float o[4];
#pragma unroll
        for (int k = 0; k < 4; ++k) {
            float uv = su[orow + 4][px0o + k + 4];
            float fv = fminf(fmaxf(fb[gy * WW + gx + k], 1e-4f), 1.0f);
            float reac = lam * (uv - fv) / (uv + 0.05f);
            o[k] = fminf(fmaxf(uv - dif[k] - reac, 0.f), 1.f);
        }
        *(float4*)&ob[gy * WW + gx] = make_float4(o[0], o[1], o[2], o[3]);
    }
}

extern "C" void kernel_launch(void* const* d_in, const int* in_sizes, int n_in,
                              void* d_out, int out_size, void* d_ws, size_t ws_size,
                              hipStream_t stream) {
    const float* u = (const float*)d_in[0];
    const float* f = (const float*)d_in[1];
    const float* filt = (const float*)d_in[2];
    const float* mu = (const float*)d_in[3];
    const float* wts = (const float*)d_in[4];
    const float* lam = (const float*)d_in[5];
    float* ws = (float*)d_ws;
    float* out = (float*)d_out;

    const bool use_ws = ws_size >= (size_t)((WS_LUT + NF * LUTN) * sizeof(float));

    zero_ws_kernel<<<1, 64, 0, stream>>>(ws);
    reduce_m_kernel<<<1024, 256, 0, stream>>>(u, ws);
    dim3 grid(WW / TILE, HH / TILE, NBATCH);
    if (use_ws) {
        lut_kernel<<<NF, 256, 0, stream>>>(filt, mu, wts, ws);
        tnrd_kernel<true><<<grid, 256, 0, stream>>>(u, f, filt, mu, wts, lam, ws, out);
    } else {
        tnrd_kernel<false><<<grid, 256, 0, stream>>>(u, f, filt, mu, wts, lam, ws, out);
    }
}

// Round 4
// 258.268 us; speedup vs baseline: 2.7915x; 1.2389x over previous
//
#include <hip/hip_runtime.h>
#include <hip/hip_fp16.h>
#include <math.h>

#define NBATCH 8
#define HH 512
#define WW 512
#define NF 24
#define NB 31
#define TH 64
#define TW 128
#define SPH (TH + 4)      // 68
#define SPW (TW + 4)      // 132
#define UH (TH + 8)       // 72
#define UW (TW + 8)       // 136
#define SU_S UW           // 136 (mult of 4 -> aligned b128 rows)
#define SP_S SPW          // 132
#define NTHR 576
#define SP_TASKS ((SPH / 4) * (SPW / 4))   // 17*33 = 561
#define CV_TASKS ((TH / 4) * (TW / 4))     // 16*32 = 512
#define LUTN 256
#define WS_LO 8
#define WS_SC 40
#define WS_LUT 72

__global__ void zero_ws_kernel(float* ws) { if (threadIdx.x == 0) ws[0] = 0.f; }

// sum over all pixels of clip(u) * (#pool windows covering pixel)/9 == sum(u_sigma)
__global__ __launch_bounds__(256) void reduce_m_kernel(const float* __restrict__ u,
                                                       float* __restrict__ ws) {
    const int N = NBATCH * HH * WW;
    int stride = gridDim.x * blockDim.x;
    float s = 0.f;
    for (int i = blockIdx.x * blockDim.x + threadIdx.x; i < N; i += stride) {
        int x = i & (WW - 1);
        int y = (i >> 9) & (HH - 1);
        float v = fminf(fmaxf(u[i], 1e-4f), 1.0f);
        float wy = (y == 0 || y == HH - 1) ? 2.f : 3.f;
        float wx = (x == 0 || x == WW - 1) ? 2.f : 3.f;
        s += v * (wy * wx);
    }
#pragma unroll
    for (int off = 32; off > 0; off >>= 1) s += __shfl_down(s, off, 64);
    if ((threadIdx.x & 63) == 0) atomicAdd(ws, s);
}

// Per-filter phi LUT, fp16-packed pairs (phi[i], phi[i+1]) in one u32.
// Range must cover zero-padded borders: contribution per tap in [min(k,0),max(k,0)].
__global__ __launch_bounds__(256) void lut_kernel(const float* __restrict__ filt,
                                                  const float* __restrict__ mu,
                                                  const float* __restrict__ wts,
                                                  float* __restrict__ ws) {
    const int c = blockIdx.x;
    const int t = threadIdx.x;
    float lo = 0.f, hi = 0.f;
    for (int i = 0; i < 25; ++i) {
        float k = filt[c * 25 + i];
        lo += fminf(k, 0.f);
        hi += fmaxf(k, 0.f);
    }
    float rng = fmaxf(hi - lo, 1e-9f);
    float h = rng * (1.f / 255.f);
    float x0 = lo + (float)t * h;
    float p[2];
#pragma unroll
    for (int s = 0; s < 2; ++s) {
        float x = x0 + (float)s * h;
        float phi = 0.f;
        for (int j = 0; j < NB; ++j) {
            float d = x - mu[c * NB + j];
            phi += wts[c * NB + j] * expf(-2.f * d * d);
        }
        p[s] = phi;
    }
    unsigned u0 = (unsigned)__half_as_ushort(__float2half(p[0]));
    unsigned u1 = (unsigned)__half_as_ushort(__float2half(p[1]));
    ((unsigned*)ws)[WS_LUT + c * LUTN + t] = u0 | (u1 << 16);
    if (t == 0) { ws[WS_LO + c] = lo; ws[WS_SC + c] = 255.f / rng; }
}

template <bool WSLUT>
__global__ __launch_bounds__(NTHR) void tnrd_kernel(
    const float* __restrict__ u, const float* __restrict__ f,
    const float* __restrict__ filt, const float* __restrict__ mu,
    const float* __restrict__ wts, const float* __restrict__ lamp,
    const float* __restrict__ ws, float* __restrict__ out)
{
    __shared__ float su[UH][SU_S];
    __shared__ float sp[SPH][SP_S];
    __shared__ unsigned slut[NF][LUTN];
    __shared__ float slo[NF];
    __shared__ float ssc[NF];

    const int tid = threadIdx.x;
    const int bz = blockIdx.z;
    const int oy0 = blockIdx.y * TH;
    const int ox0 = blockIdx.x * TW;
    const float* ub = u + bz * HH * WW;

    // ---- stage clipped u tile (halo 4); zero outside image. 72*136 = 576*17
#pragma unroll
    for (int j = 0; j < (UH * UW) / NTHR; ++j) {
        int i = j * NTHR + tid;
        int uy = i / UW, ux = i - uy * UW;
        int gy = oy0 - 4 + uy, gx = ox0 - 4 + ux;
        float v = 0.f;
        if ((unsigned)gy < (unsigned)HH && (unsigned)gx < (unsigned)WW)
            v = fminf(fmaxf(ub[gy * WW + gx], 1e-4f), 1.0f);
        su[uy][ux] = v;
    }

    // ---- LUT into LDS
    if (WSLUT) {
        const unsigned* lsrc = (const unsigned*)ws + WS_LUT;
        for (int i = tid; i < NF * LUTN; i += NTHR) (&slut[0][0])[i] = lsrc[i];
        if (tid < NF) { slo[tid] = ws[WS_LO + tid]; ssc[tid] = ws[WS_SC + tid]; }
    } else {
        for (int k = 0; k < NF; ++k) {
            float lo = 0.f, hi = 0.f;
            for (int i = 0; i < 25; ++i) {
                float kv = filt[k * 25 + i];
                lo += fminf(kv, 0.f);
                hi += fmaxf(kv, 0.f);
            }
            float rng = fmaxf(hi - lo, 1e-9f);
            float h = rng * (1.f / 255.f);
            if (tid < LUTN) {
                float p[2];
#pragma unroll
                for (int s = 0; s < 2; ++s) {
                    float x = lo + (float)(tid + s) * h;
                    float phi = 0.f;
                    for (int j = 0; j < NB; ++j) {
                        float d = x - mu[k * NB + j];
                        phi += wts[k * NB + j] * __expf(-2.f * d * d);
                    }
                    p[s] = phi;
                }
                unsigned u0 = (unsigned)__half_as_ushort(__float2half(p[0]));
                unsigned u1 = (unsigned)__half_as_ushort(__float2half(p[1]));
                slut[k][tid] = u0 | (u1 << 16);
            }
            if (tid == 0) { slo[k] = lo; ssc[k] = 255.f / rng; }
        }
    }
    __syncthreads();

    const float Mv = ws[0] * (1.0f / (9.0f * NBATCH * HH * WW)) + 0.001f;
    const float inv9M = (1.f / 9.f) / Mv;

    // ---- task decode
    const int qr = tid / (SPW / 4);           // sp 4x4 patch row (0..16)
    const int qc = tid - qr * (SPW / 4);      // 0..32
    const int pr0 = qr * 4, pc0 = qc * 4;     // sp coords
    const int tr = tid >> 5, tc = tid & 31;   // conv2 4x4 patch (tid<512)
    const int or0 = tr * 4, oc0 = tc * 4;     // output coords in tile

    // ---- u_sigma/M for own sp patch, in registers (masked to image)
    float usg[4][4];
    if (tid < SP_TASKS) {
        float hr[6][4];
#pragma unroll
        for (int j = 0; j < 6; ++j) {
            float4 a = *(const float4*)&su[pr0 + 1 + j][pc0];
            float4 b = *(const float4*)&su[pr0 + 1 + j][pc0 + 4];
            float t8[8] = {a.x, a.y, a.z, a.w, b.x, b.y, b.z, b.w};
#pragma unroll
            for (int k = 0; k < 4; ++k)
                hr[j][k] = t8[k + 1] + t8[k + 2] + t8[k + 3];
        }
#pragma unroll
        for (int r = 0; r < 4; ++r) {
            int gy = oy0 - 2 + pr0 + r;
            bool ry = (unsigned)gy < (unsigned)HH;
#pragma unroll
            for (int k = 0; k < 4; ++k) {
                int gx = ox0 - 2 + pc0 + k;
                bool ok = ry && (unsigned)gx < (unsigned)WW;
                usg[r][k] = ok ? (hr[r][k] + hr[r + 1][k] + hr[r + 2][k]) * inv9M : 0.f;
            }
        }
    }

    float dif[4][4] = {{0.f}};

    for (int c = 0; c < NF; ++c) {
        const float* fc = filt + c * 25;      // uniform -> SGPR
        const unsigned* slc = &slut[c][0];
        const float scc = ssc[c];
        const float offc = -slo[c] * scc;

        if (tid < SP_TASKS) {
            float acc[4][4] = {{0.f}};
#pragma unroll
            for (int ky = 0; ky < 8; ++ky) {
                float4 a = *(const float4*)&su[pr0 + ky][pc0];
                float4 b = *(const float4*)&su[pr0 + ky][pc0 + 4];
                float t8[8] = {a.x, a.y, a.z, a.w, b.x, b.y, b.z, b.w};
#pragma unroll
                for (int r = 0; r < 4; ++r) {
                    if (ky - r < 0 || ky - r > 4) continue;
                    const int kyy = ky - r;
#pragma unroll
                    for (int dx = 0; dx < 5; ++dx) {
                        float w = fc[kyy * 5 + dx];
#pragma unroll
                        for (int k = 0; k < 4; ++k)
                            acc[r][k] = fmaf(w, t8[k + dx], acc[r][k]);
                    }
                }
            }
#pragma unroll
            for (int r = 0; r < 4; ++r) {
                float o[4];
#pragma unroll
                for (int k = 0; k < 4; ++k) {
                    float t = fmaf(acc[r][k], scc, offc);
                    t = fminf(fmaxf(t, 0.f), 254.999f);
                    int i0 = (int)t;
                    float fr = t - (float)i0;
                    unsigned pk = slc[i0];
                    __half2 hv = *reinterpret_cast<__half2*>(&pk);
                    float2 fv = __half22float2(hv);
                    o[k] = fmaf(fr, fv.y - fv.x, fv.x) * usg[r][k];
                }
                *(float4*)&sp[pr0 + r][pc0] = make_float4(o[0], o[1], o[2], o[3]);
            }
        }
        __syncthreads();

        if (tid < CV_TASKS) {
#pragma unroll
            for (int s = 0; s < 8; ++s) {
                float4 a = *(const float4*)&sp[or0 + s][oc0];
                float4 b = *(const float4*)&sp[or0 + s][oc0 + 4];
                float t8[8] = {a.x, a.y, a.z, a.w, b.x, b.y, b.z, b.w};
#pragma unroll
                for (int r = 0; r < 4; ++r) {
                    if (s - r < 0 || s - r > 4) continue;
                    const int dy = s - r;
#pragma unroll
                    for (int dx = 0; dx < 5; ++dx) {
                        float w = fc[(4 - dy) * 5 + (4 - dx)];
#pragma unroll
                        for (int k = 0; k < 4; ++k)
                            dif[r][k] = fmaf(w, t8[k + dx], dif[r][k]);
                    }
                }
            }
        }
        __syncthreads();
    }

    // ---- epilogue
    if (tid < CV_TASKS) {
        const float lam = lamp[0];
        const float* fb = f + bz * HH * WW;
        float* ob = out + bz * HH * WW;
#pragma unroll
        for (int r = 0; r < 4; ++r) {
            int gy = oy0 + or0 + r;
            int gx = ox0 + oc0;
            float4 uv4 = *(const float4*)&su[or0 + r + 4][oc0 + 4];
            float4 fv4 = *(const float4*)&fb[gy * WW + gx];
            float uu[4] = {uv4.x, uv4.y, uv4.z, uv4.w};
            float ff[4] = {fv4.x, fv4.y, fv4.z, fv4.w};
            float o[4];
#pragma unroll
            for (int k = 0; k < 4; ++k) {
                float uv = uu[k];
                float fv = fminf(fmaxf(ff[k], 1e-4f), 1.0f);
                float reac = lam * (uv - fv) / (uv + 0.05f);
                o[k] = fminf(fmaxf(uv - dif[r][k] - reac, 0.f), 1.f);
            }
            *(float4*)&ob[gy * WW + gx] = make_float4(o[0], o[1], o[2], o[3]);
        }
    }
}

extern "C" void kernel_launch(void* const* d_in, const int* in_sizes, int n_in,
                              void* d_out, int out_size, void* d_ws, size_t ws_size,
                              hipStream_t stream) {
    const float* u = (const float*)d_in[0];
    const float* f = (const float*)d_in[1];
    const float* filt = (const float*)d_in[2];
    const float* mu = (const float*)d_in[3];
    const float* wts = (const float*)d_in[4];
    const float* lam = (const float*)d_in[5];
    float* ws = (float*)d_ws;
    float* out = (float*)d_out;

    const bool use_ws = ws_size >= (size_t)((WS_LUT + NF * LUTN) * sizeof(float));

    zero_ws_kernel<<<1, 64, 0, stream>>>(ws);
    reduce_m_kernel<<<1024, 256, 0, stream>>>(u, ws);
    dim3 grid(WW / TW, HH / TH, NBATCH);
    if (use_ws) {
        lut_kernel<<<NF, 256, 0, stream>>>(filt, mu, wts, ws);
        tnrd_kernel<true><<<grid, NTHR, 0, stream>>>(u, f, filt, mu, wts, lam, ws, out);
    } else {
        tnrd_kernel<false><<<grid, NTHR, 0, stream>>>(u, f, filt, mu, wts, lam, ws, out);
    }
}

// Round 6
// 218.768 us; speedup vs baseline: 3.2956x; 1.1806x over previous
//
#include <hip/hip_runtime.h>
#include <hip/hip_fp16.h>
#include <math.h>

#define NBATCH 8
#define HH 512
#define WW 512
#define NF 24
#define NB 31
#define TH 32
#define TW 64
#define SPH (TH + 4)   // 36
#define SPW (TW + 4)   // 68
#define UH (TH + 8)    // 40
#define UW (TW + 8)    // 72
#define SU_S 76        // padded stride: 4-row groups offset 16 mod 32 banks
#define SP_S 76
#define NTHR 192
#define SP_TASKS 153   // (36/4)*(68/4) = 9*17
#define CV_TASKS 128   // (32/4)*(64/4) = 8*16
#define LUTN 256
#define WS_LO 8
#define WS_SC 40
#define WS_LUT 72                        // u32-indexed
#define WS_PART (WS_LUT + NF * LUTN)     // 6216
#define WS_REQ ((WS_PART + 1024) * 4)    // 28960 bytes

__device__ __forceinline__ void phi_pair(const float* mu, const float* wts, int c,
                                         float x, float h, float* p0, float* p1) {
    float a = 0.f, b = 0.f;
    for (int j = 0; j < NB; ++j) {
        float m = mu[c * NB + j], w = wts[c * NB + j];
        float d0 = x - m, d1 = x + h - m;
        a += w * __expf(-2.f * d0 * d0);
        b += w * __expf(-2.f * d1 * d1);
    }
    *p0 = a; *p1 = b;
}

__device__ __forceinline__ void filter_range(const float* filt, int c,
                                             float* lo_, float* rng_) {
    float lo = 0.f, hi = 0.f;
    for (int i = 0; i < 25; ++i) {
        float k = filt[c * 25 + i];
        lo += fminf(k, 0.f);
        hi += fmaxf(k, 0.f);
    }
    *lo_ = lo;
    *rng_ = fmaxf(hi - lo, 1e-9f);
}

// fused pre-pass: per-block M partials (all blocks) + phi LUTs (blocks 0..23)
__global__ __launch_bounds__(256) void pre_kernel(const float* __restrict__ u,
                                                  const float* __restrict__ filt,
                                                  const float* __restrict__ mu,
                                                  const float* __restrict__ wts,
                                                  float* __restrict__ ws, int do_lut) {
    __shared__ float sred[4];
    const int tid = threadIdx.x;
    const int N = NBATCH * HH * WW;
    int stride = gridDim.x * blockDim.x;
    float s = 0.f;
    for (int i = blockIdx.x * blockDim.x + tid; i < N; i += stride) {
        int x = i & (WW - 1);
        int y = (i >> 9) & (HH - 1);
        float v = fminf(fmaxf(u[i], 1e-4f), 1.0f);
        float wy = (y == 0 || y == HH - 1) ? 2.f : 3.f;
        float wx = (x == 0 || x == WW - 1) ? 2.f : 3.f;
        s += v * (wy * wx);
    }
#pragma unroll
    for (int off = 32; off > 0; off >>= 1) s += __shfl_down(s, off, 64);
    if ((tid & 63) == 0) sred[tid >> 6] = s;
    __syncthreads();
    if (tid == 0) ws[WS_PART + blockIdx.x] = sred[0] + sred[1] + sred[2] + sred[3];

    if (do_lut && blockIdx.x < NF) {
        const int c = blockIdx.x;
        float lo, rng;
        filter_range(filt, c, &lo, &rng);
        float h = rng * (1.f / 255.f);
        float p0, p1;
        phi_pair(mu, wts, c, lo + (float)tid * h, h, &p0, &p1);
        unsigned u0 = (unsigned)__half_as_ushort(__float2half(p0));
        unsigned u1 = (unsigned)__half_as_ushort(__float2half(p1));
        ((unsigned*)ws)[WS_LUT + c * LUTN + tid] = u0 | (u1 << 16);
        if (tid == 0) { ws[WS_LO + c] = lo; ws[WS_SC + c] = 255.f / rng; }
    }
}

__device__ __forceinline__ void sp_phase(int pr0, int pc0,
                                         const float (*su)[SU_S], float (*spb)[SP_S],
                                         const unsigned* __restrict__ slc,
                                         float scc, float offc,
                                         const float* __restrict__ fc,
                                         const float (&usg)[4][4]) {
    float acc[4][4] = {{0.f}};
#pragma unroll
    for (int ky = 0; ky < 8; ++ky) {
        float4 a = *(const float4*)&su[pr0 + ky][pc0];
        float4 b = *(const float4*)&su[pr0 + ky][pc0 + 4];
        float t8[8] = {a.x, a.y, a.z, a.w, b.x, b.y, b.z, b.w};
#pragma unroll
        for (int r = 0; r < 4; ++r) {
            if (ky - r < 0 || ky - r > 4) continue;
            const int kyy = ky - r;
#pragma unroll
            for (int dx = 0; dx < 5; ++dx) {
                float w = fc[kyy * 5 + dx];
#pragma unroll
                for (int k = 0; k < 4; ++k)
                    acc[r][k] = fmaf(w, t8[k + dx], acc[r][k]);
            }
        }
    }
#pragma unroll
    for (int r = 0; r < 4; ++r) {
        float o[4];
#pragma unroll
        for (int k = 0; k < 4; ++k) {
            float t = fmaf(acc[r][k], scc, offc);
            t = fminf(fmaxf(t, 0.f), 254.999f);
            int i0 = (int)t;
            float fr = t - (float)i0;
            unsigned pk = slc[i0];
            __half2 hv = *reinterpret_cast<const __half2*>(&pk);
            float2 fv = __half22float2(hv);
            o[k] = fmaf(fr, fv.y - fv.x, fv.x) * usg[r][k];
        }
        *(float4*)&spb[pr0 + r][pc0] = make_float4(o[0], o[1], o[2], o[3]);
    }
}

template <bool WSLUT>
__global__ __launch_bounds__(NTHR) void tnrd_kernel(
    const float* __restrict__ u, const float* __restrict__ f,
    const float* __restrict__ filt, const float* __restrict__ mu,
    const float* __restrict__ wts, const float* __restrict__ lamp,
    const float* __restrict__ ws, float* __restrict__ out)
{
    __shared__ float su[UH][SU_S];
    __shared__ float sp[2][SPH][SP_S];
    __shared__ unsigned slut[2][LUTN];
    __shared__ float swred[3];

    const int tid = threadIdx.x;
    const int bz = blockIdx.z;
    const int oy0 = blockIdx.y * TH;
    const int ox0 = blockIdx.x * TW;
    const float* ub = u + bz * HH * WW;
    const unsigned* lutg = (const unsigned*)ws + WS_LUT;

    // ---- stage clipped u tile (halo 4); zero outside image. 40*72 = 192*15
#pragma unroll
    for (int j = 0; j < (UH * UW) / NTHR; ++j) {
        int i = j * NTHR + tid;
        int uy = i / UW, ux = i - uy * UW;
        int gy = oy0 - 4 + uy, gx = ox0 - 4 + ux;
        float v = 0.f;
        if ((unsigned)gy < (unsigned)HH && (unsigned)gx < (unsigned)WW)
            v = fminf(fmaxf(ub[gy * WW + gx], 1e-4f), 1.0f);
        su[uy][ux] = v;
    }

    // ---- LUTs for filters 0,1
    if (WSLUT) {
        for (int i = tid; i < 2 * LUTN; i += NTHR) (&slut[0][0])[i] = lutg[i];
    } else {
        for (int c = 0; c < 2; ++c) {
            float lo, rng;
            filter_range(filt, c, &lo, &rng);
            float h = rng * (1.f / 255.f);
            for (int e = tid; e < LUTN; e += NTHR) {
                float p0, p1;
                phi_pair(mu, wts, c, lo + (float)e * h, h, &p0, &p1);
                unsigned u0 = (unsigned)__half_as_ushort(__float2half(p0));
                unsigned u1 = (unsigned)__half_as_ushort(__float2half(p1));
                slut[c][e] = u0 | (u1 << 16);
            }
        }
    }

    // ---- M from partials (no atomic, no zero-init needed)
    {
        float ps = 0.f;
        for (int i = tid; i < 1024; i += NTHR) ps += ws[WS_PART + i];
#pragma unroll
        for (int off = 32; off > 0; off >>= 1) ps += __shfl_down(ps, off, 64);
        if ((tid & 63) == 0) swred[tid >> 6] = ps;
    }
    __syncthreads();

    const float tot = swred[0] + swred[1] + swred[2];
    const float Mv = tot * (1.0f / (9.0f * NBATCH * HH * WW)) + 0.001f;
    const float inv9M = (1.f / 9.f) / Mv;

    // ---- task decode
    const int qr = tid / 17, qc = tid - qr * 17;     // sp patch (tid<153)
    const int pr0 = qr * 4, pc0 = qc * 4;
    const int tr = tid >> 4, tc = tid & 15;          // conv2 patch (tid<128)
    const int or0 = tr * 4, oc0 = tc * 4;

    // ---- u_sigma/M for own sp patch, in registers (masked to image)
    float usg[4][4];
    if (tid < SP_TASKS) {
        float hr[6][4];
#pragma unroll
        for (int j = 0; j < 6; ++j) {
            float4 a = *(const float4*)&su[pr0 + 1 + j][pc0];
            float4 b = *(const float4*)&su[pr0 + 1 + j][pc0 + 4];
            float t8[8] = {a.x, a.y, a.z, a.w, b.x, b.y, b.z, b.w};
#pragma unroll
            for (int k = 0; k < 4; ++k)
                hr[j][k] = t8[k + 1] + t8[k + 2] + t8[k + 3];
        }
#pragma unroll
        for (int r = 0; r < 4; ++r) {
            int gy = oy0 - 2 + pr0 + r;
            bool ry = (unsigned)gy < (unsigned)HH;
#pragma unroll
            for (int k = 0; k < 4; ++k) {
                int gx = ox0 - 2 + pc0 + k;
                bool ok = ry && (unsigned)gx < (unsigned)WW;
                usg[r][k] = ok ? (hr[r][k] + hr[r + 1][k] + hr[r + 2][k]) * inv9M : 0.f;
            }
        }
    }

    // ---- prologue: sp(0)
    if (tid < SP_TASKS) {
        float lo, scc;
        if (WSLUT) { lo = ws[WS_LO]; scc = ws[WS_SC]; }
        else { float rng; filter_range(filt, 0, &lo, &rng); scc = 255.f / rng; }
        sp_phase(pr0, pc0, su, sp[0], &slut[0][0], scc, -lo * scc, filt, usg);
    }
    __syncthreads();

    float dif[4][4] = {{0.f}};

    // ---- main loop: ONE barrier per filter
    for (int c = 0; c < NF; ++c) {
        // (a) sp-phase for filter c+1 into sp[(c+1)&1]
        if (c + 1 < NF && tid < SP_TASKS) {
            int cn = c + 1;
            float lo, scc;
            if (WSLUT) { lo = ws[WS_LO + cn]; scc = ws[WS_SC + cn]; }
            else { float rng; filter_range(filt, cn, &lo, &rng); scc = 255.f / rng; }
            sp_phase(pr0, pc0, su, sp[cn & 1], &slut[cn & 1][0],
                     scc, -lo * scc, filt + cn * 25, usg);
        }

        // (b) conv2 for filter c from sp[c&1]
        if (tid < CV_TASKS) {
            const float* fc = filt + c * 25;
            const float (*spc)[SP_S] = sp[c & 1];
#pragma unroll
            for (int s = 0; s < 8; ++s) {
                float4 a = *(const float4*)&spc[or0 + s][oc0];
                float4 b = *(const float4*)&spc[or0 + s][oc0 + 4];
                float t8[8] = {a.x, a.y, a.z, a.w, b.x, b.y, b.z, b.w};
#pragma unroll
                for (int r = 0; r < 4; ++r) {
                    if (s - r < 0 || s - r > 4) continue;
                    const int dy = s - r;
#pragma unroll
                    for (int dx = 0; dx < 5; ++dx) {
                        float w = fc[(4 - dy) * 5 + (4 - dx)];
#pragma unroll
                        for (int k = 0; k < 4; ++k)
                            dif[r][k] = fmaf(w, t8[k + dx], dif[r][k]);
                    }
                }
            }
        } else if (c + 2 < NF) {
            // (c) wave 2 (tid 128..191): LUT for filter c+2 into slut[(c+2)&1]
            int t = tid - CV_TASKS;   // 0..63
            int cn = c + 2;
            if (WSLUT) {
#pragma unroll
                for (int j = 0; j < 4; ++j)
                    slut[cn & 1][t + 64 * j] = lutg[cn * LUTN + t + 64 * j];
            } else {
                float lo, rng;
                filter_range(filt, cn, &lo, &rng);
                float h = rng * (1.f / 255.f);
#pragma unroll
                for (int j = 0; j < 4; ++j) {
                    int e = t + 64 * j;
                    float p0, p1;
                    phi_pair(mu, wts, cn, lo + (float)e * h, h, &p0, &p1);
                    unsigned u0 = (unsigned)__half_as_ushort(__float2half(p0));
                    unsigned u1 = (unsigned)__half_as_ushort(__float2half(p1));
                    slut[cn & 1][e] = u0 | (u1 << 16);
                }
            }
        }

        if (c + 1 < NF) __syncthreads();
    }

    // ---- epilogue
    if (tid < CV_TASKS) {
        const float lam = lamp[0];
        const float* fb = f + bz * HH * WW;
        float* ob = out + bz * HH * WW;
#pragma unroll
        for (int r = 0; r < 4; ++r) {
            int gy = oy0 + or0 + r;
            int gx = ox0 + oc0;
            float4 uv4 = *(const float4*)&su[or0 + r + 4][oc0 + 4];
            float4 fv4 = *(const float4*)&fb[gy * WW + gx];
            float uu[4] = {uv4.x, uv4.y, uv4.z, uv4.w};
            float ff[4] = {fv4.x, fv4.y, fv4.z, fv4.w};
            float o[4];
#pragma unroll
            for (int k = 0; k < 4; ++k) {
                float uv = uu[k];
                float fv = fminf(fmaxf(ff[k], 1e-4f), 1.0f);
                float reac = lam * (uv - fv) / (uv + 0.05f);
                o[k] = fminf(fmaxf(uv - dif[r][k] - reac, 0.f), 1.f);
            }
            *(float4*)&ob[gy * WW + gx] = make_float4(o[0], o[1], o[2], o[3]);
        }
    }
}

extern "C" void kernel_launch(void* const* d_in, const int* in_sizes, int n_in,
                              void* d_out, int out_size, void* d_ws, size_t ws_size,
                              hipStream_t stream) {
    const float* u = (const float*)d_in[0];
    const float* f = (const float*)d_in[1];
    const float* filt = (const float*)d_in[2];
    const float* mu = (const float*)d_in[3];
    const float* wts = (const float*)d_in[4];
    const float* lam = (const float*)d_in[5];
    float* ws = (float*)d_ws;
    float* out = (float*)d_out;

    const bool use_ws = ws_size >= (size_t)WS_REQ;
    pre_kernel<<<1024, 256, 0, stream>>>(u, filt, mu, wts, ws, use_ws ? 1 : 0);
    dim3 grid(WW / TW, HH / TH, NBATCH);
    if (use_ws)
        tnrd_kernel<true><<<grid, NTHR, 0, stream>>>(u, f, filt, mu, wts, lam, ws, out);
    else
        tnrd_kernel<false><<<grid, NTHR, 0, stream>>>(u, f, filt, mu, wts, lam, ws, out);
}

// Round 8
// 211.104 us; speedup vs baseline: 3.4152x; 1.0363x over previous
//
#include <hip/hip_runtime.h>
#include <hip/hip_fp16.h>
#include <math.h>

#define NBATCH 8
#define HH 512
#define WW 512
#define NF 24
#define NB 31
#define TH 32        // block tile rows = 2 wave strips
#define TW 64        // block tile cols
#define STRIP 16
#define UH 40        // TH + 8
#define UW 72        // TW + 8
#define SU_S 76      // su stride (2-row stride -> banks {0,6,4,2} spread)
#define UGH 36       // TH + 4
#define UG_S 76
#define SPH 20       // STRIP + 4
#define SP_S 72      // swizzled storage
#define NTHR 128
#define LUTN 256
#define WS_LO 8
#define WS_SC 40
#define WS_LUT 72                        // u32-indexed
#define WS_PART (WS_LUT + NF * LUTN)
#define WS_REQ ((WS_PART + 1024) * 4)

__device__ __forceinline__ void wave_lds_fence() {
    asm volatile("s_waitcnt lgkmcnt(0)" ::: "memory");
    __builtin_amdgcn_wave_barrier();
}

// sp column swizzle: XOR 4-word granule bits with row bits so the 4-apart
// conv2 row groups land on distinct bank-granule positions. Only cols <64
// (aligned 64-word block); tail cols 64..67 unswizzled. Write & read agree.
__device__ __forceinline__ int sp_col(int r, int c) {
    return (c < 64) ? (c ^ (((r >> 2) & 3) << 3)) : c;
}

__device__ __forceinline__ void phi_pair(const float* mu, const float* wts, int c,
                                         float x, float h, float* p0, float* p1) {
    float a = 0.f, b = 0.f;
    for (int j = 0; j < NB; ++j) {
        float m = mu[c * NB + j], w = wts[c * NB + j];
        float d0 = x - m, d1 = x + h - m;
        a += w * __expf(-2.f * d0 * d0);
        b += w * __expf(-2.f * d1 * d1);
    }
    *p0 = a; *p1 = b;
}

__device__ __forceinline__ void filter_range(const float* filt, int c,
                                             float* lo_, float* rng_) {
    float lo = 0.f, hi = 0.f;
    for (int i = 0; i < 25; ++i) {
        float k = filt[c * 25 + i];
        lo += fminf(k, 0.f);
        hi += fmaxf(k, 0.f);
    }
    *lo_ = lo;
    *rng_ = fmaxf(hi - lo, 1e-9f);
}

// fused pre-pass: per-block M partials (all blocks) + phi LUTs (blocks 0..23)
__global__ __launch_bounds__(256) void pre_kernel(const float* __restrict__ u,
                                                  const float* __restrict__ filt,
                                                  const float* __restrict__ mu,
                                                  const float* __restrict__ wts,
                                                  float* __restrict__ ws, int do_lut) {
    __shared__ float sred[4];
    const int tid = threadIdx.x;
    const int N = NBATCH * HH * WW;
    int stride = gridDim.x * blockDim.x;
    float s = 0.f;
    for (int i = blockIdx.x * blockDim.x + tid; i < N; i += stride) {
        int x = i & (WW - 1);
        int y = (i >> 9) & (HH - 1);
        float v = fminf(fmaxf(u[i], 1e-4f), 1.0f);
        float wy = (y == 0 || y == HH - 1) ? 2.f : 3.f;
        float wx = (x == 0 || x == WW - 1) ? 2.f : 3.f;
        s += v * (wy * wx);
    }
#pragma unroll
    for (int off = 32; off > 0; off >>= 1) s += __shfl_down(s, off, 64);
    if ((tid & 63) == 0) sred[tid >> 6] = s;
    __syncthreads();
    if (tid == 0) ws[WS_PART + blockIdx.x] = sred[0] + sred[1] + sred[2] + sred[3];

    if (do_lut && blockIdx.x < NF) {
        const int c = blockIdx.x;
        float lo, rng;
        filter_range(filt, c, &lo, &rng);
        float h = rng * (1.f / 255.f);
        float p0, p1;
        phi_pair(mu, wts, c, lo + (float)tid * h, h, &p0, &p1);
        unsigned u0 = (unsigned)__half_as_ushort(__float2half(p0));
        unsigned u1 = (unsigned)__half_as_ushort(__float2half(p1));
        ((unsigned*)ws)[WS_LUT + c * LUTN + tid] = u0 | (u1 << 16);
        if (tid == 0) { ws[WS_LO + c] = lo; ws[WS_SC + c] = 255.f / rng; }
    }
}

template <bool WSLUT>
__global__ __launch_bounds__(NTHR, 2) void tnrd_kernel(
    const float* __restrict__ u, const float* __restrict__ f,
    const float* __restrict__ filt, const float* __restrict__ mu,
    const float* __restrict__ wts, const float* __restrict__ lamp,
    const float* __restrict__ ws, float* __restrict__ out)
{
    __shared__ float su[UH][SU_S];        // clipped u, block-shared, read-only
    __shared__ float ug[UGH][UG_S];       // u_sigma/M, block-shared, read-only
    __shared__ float spb[2][SPH][SP_S];   // scaled_phi, PRIVATE per wave
    __shared__ unsigned slut[2][2][LUTN]; // LUT dbuf, PRIVATE per wave
    __shared__ float sred[2];

    const int tid = threadIdx.x;
    const int w = tid >> 6;
    const int lane = tid & 63;
    const int bz = blockIdx.z;
    const int oy0 = blockIdx.y * TH;
    const int ox0 = blockIdx.x * TW;
    const float* ub = u + bz * HH * WW;
    const unsigned* lutg = (const unsigned*)ws + WS_LUT;

    // ---- stage clipped u tile (halo 4); zero outside image
    for (int i = tid; i < UH * UW; i += NTHR) {
        int uy = i / UW, ux = i - uy * UW;
        int gy = oy0 - 4 + uy, gx = ox0 - 4 + ux;
        float v = 0.f;
        if ((unsigned)gy < (unsigned)HH && (unsigned)gx < (unsigned)WW)
            v = fminf(fmaxf(ub[gy * WW + gx], 1e-4f), 1.0f);
        su[uy][ux] = v;
    }

    // ---- M from partials
    {
        float ps = 0.f;
#pragma unroll
        for (int j = 0; j < 1024 / NTHR; ++j) ps += ws[WS_PART + j * NTHR + tid];
#pragma unroll
        for (int off = 32; off > 0; off >>= 1) ps += __shfl_down(ps, off, 64);
        if (lane == 0) sred[w] = ps;
    }

    // ---- initial LUT (filter 0) into this wave's buffer 0
    if (WSLUT) {
        ((uint4*)&slut[w][0][0])[lane] = ((const uint4*)lutg)[lane];
    }
    __syncthreads();   // su + sred complete

    const float tot = sred[0] + sred[1];
    const float Mv = tot * (1.0f / (9.0f * NBATCH * HH * WW)) + 0.001f;
    const float inv9M = (1.f / 9.f) / Mv;

    // ---- usig (u_sigma/M) on the 36x68 block sp-region; zero outside image
    for (int i = tid; i < UGH * 17; i += NTHR) {
        int r = i / 17, t = i - r * 17;
        int c0 = 4 * t;
        float s4[4] = {0.f, 0.f, 0.f, 0.f};
#pragma unroll
        for (int dy = 0; dy < 3; ++dy) {
            float4 a = *(const float4*)&su[r + 1 + dy][c0];
            float4 b = *(const float4*)&su[r + 1 + dy][c0 + 4];
            float t8[8] = {a.x, a.y, a.z, a.w, b.x, b.y, b.z, b.w};
#pragma unroll
            for (int k = 0; k < 4; ++k) s4[k] += t8[k + 1] + t8[k + 2] + t8[k + 3];
        }
        int gy = oy0 - 2 + r;
        bool ry = (unsigned)gy < (unsigned)HH;
        float o[4];
#pragma unroll
        for (int k = 0; k < 4; ++k) {
            int gx = ox0 - 2 + c0 + k;
            o[k] = (ry && (unsigned)gx < (unsigned)WW) ? s4[k] * inv9M : 0.f;
        }
        *(float4*)&ug[r][c0] = make_float4(o[0], o[1], o[2], o[3]);
    }
    __syncthreads();   // ug complete — LAST block-wide barrier

    // ---- per-wave autonomous filter loop
    float dif[4][4] = {{0.f}};
    const int or0 = 4 * (lane >> 4);     // conv2 4x4 task
    const int oc0 = 4 * (lane & 15);
    const int wy = w * STRIP;
    float (*spw)[SP_S] = spb[w];

    for (int c = 0; c < NF; ++c) {
        const float* fc = filt + c * 25;   // uniform -> SGPR
        float lo, scc;
        uint4 nlut;
        const bool havepre = WSLUT && (c + 1 < NF);
        if (havepre) nlut = ((const uint4*)(lutg + (c + 1) * LUTN))[lane];
        if (WSLUT) {
            lo = ws[WS_LO + c]; scc = ws[WS_SC + c];
        } else {
            float rng; filter_range(filt, c, &lo, &rng); scc = 255.f / rng;
            float h = rng * (1.f / 255.f);
            for (int e = lane; e < LUTN; e += 64) {
                float p0, p1;
                phi_pair(mu, wts, c, lo + (float)e * h, h, &p0, &p1);
                unsigned u0 = (unsigned)__half_as_ushort(__float2half(p0));
                unsigned u1 = (unsigned)__half_as_ushort(__float2half(p1));
                slut[w][c & 1][e] = u0 | (u1 << 16);
            }
        }
        const float offc = -lo * scc;
        const unsigned* sl = &slut[w][c & 1][0];
        wave_lds_fence();   // LUT writes (prev iter / fallback) visible

        // sp phase: 170 2x4 tasks over this wave's 20x68 region
#pragma unroll
        for (int p = 0; p < 3; ++p) {
            int task = p * 64 + lane;
            if (task < 170) {
                int tr = task / 17, tc2 = task - tr * 17;
                int sr0 = 2 * tr, sc0 = 4 * tc2;
                float acc[2][4] = {{0.f}};
#pragma unroll
                for (int ky = 0; ky < 6; ++ky) {
                    float4 a = *(const float4*)&su[wy + sr0 + ky][sc0];
                    float4 b = *(const float4*)&su[wy + sr0 + ky][sc0 + 4];
                    float t8[8] = {a.x, a.y, a.z, a.w, b.x, b.y, b.z, b.w};
#pragma unroll
                    for (int r = 0; r < 2; ++r) {
                        int kyy = ky - r;
                        if (kyy < 0 || kyy > 4) continue;
#pragma unroll
                        for (int dx = 0; dx < 5; ++dx) {
                            float wgt = fc[kyy * 5 + dx];
#pragma unroll
                            for (int k = 0; k < 4; ++k)
                                acc[r][k] = fmaf(wgt, t8[k + dx], acc[r][k]);
                        }
                    }
                }
#pragma unroll
                for (int r = 0; r < 2; ++r) {
                    float4 uu = *(const float4*)&ug[wy + sr0 + r][sc0];
                    float uu4[4] = {uu.x, uu.y, uu.z, uu.w};
                    float o[4];
#pragma unroll
                    for (int k = 0; k < 4; ++k) {
                        float t = fmaf(acc[r][k], scc, offc);
                        t = fminf(fmaxf(t, 0.f), 254.999f);
                        int i0 = (int)t;
                        float fr = t - (float)i0;
                        unsigned pk = sl[i0];
                        __half2 hv = *reinterpret_cast<const __half2*>(&pk);
                        float2 fv = __half22float2(hv);
                        o[k] = fmaf(fr, fv.y - fv.x, fv.x) * uu4[k];
                    }
                    *(float4*)&spw[sr0 + r][sp_col(sr0 + r, sc0)] =
                        make_float4(o[0], o[1], o[2], o[3]);
                }
            }
        }
        wave_lds_fence();   // sp writes visible to this wave's conv2

        // conv2: accumulate diffusion for own 4x4 output patch
#pragma unroll
        for (int s = 0; s < 8; ++s) {
            int rr = or0 + s;
            float4 a = *(const float4*)&spw[rr][sp_col(rr, oc0)];
            float4 b = *(const float4*)&spw[rr][sp_col(rr, oc0 + 4)];
            float t8[8] = {a.x, a.y, a.z, a.w, b.x, b.y, b.z, b.w};
#pragma unroll
            for (int r = 0; r < 4; ++r) {
                int dy = s - r;
                if (dy < 0 || dy > 4) continue;
#pragma unroll
                for (int dx = 0; dx < 5; ++dx) {
                    float wgt = fc[(4 - dy) * 5 + (4 - dx)];
#pragma unroll
                    for (int k = 0; k < 4; ++k)
                        dif[r][k] = fmaf(wgt, t8[k + dx], dif[r][k]);
                }
            }
        }

        // store prefetched next-filter LUT into the other buffer
        if (havepre) ((uint4*)&slut[w][(c + 1) & 1][0])[lane] = nlut;
    }

    // ---- epilogue
    {
        const float lam = lamp[0];
        const float* fb = f + bz * HH * WW;
        float* ob = out + bz * HH * WW;
#pragma unroll
        for (int r = 0; r < 4; ++r) {
            int gy = oy0 + wy + or0 + r;
            int gx = ox0 + oc0;
            float4 uv4 = *(const float4*)&su[wy + or0 + r + 4][oc0 + 4];
            float4 fv4 = *(const float4*)&fb[gy * WW + gx];
            float uu[4] = {uv4.x, uv4.y, uv4.z, uv4.w};
            float ff[4] = {fv4.x, fv4.y, fv4.z, fv4.w};
            float o[4];
#pragma unroll
            for (int k = 0; k < 4; ++k) {
                float uv = uu[k];
                float fv = fminf(fmaxf(ff[k], 1e-4f), 1.0f);
                float reac = lam * (uv - fv) / (uv + 0.05f);
                o[k] = fminf(fmaxf(uv - dif[r][k] - reac, 0.f), 1.f);
            }
            *(float4*)&ob[gy * WW + gx] = make_float4(o[0], o[1], o[2], o[3]);
        }
    }
}

extern "C" void kernel_launch(void* const* d_in, const int* in_sizes, int n_in,
                              void* d_out, int out_size, void* d_ws, size_t ws_size,
                              hipStream_t stream) {
    const float* u = (const float*)d_in[0];
    const float* f = (const float*)d_in[1];
    const float* filt = (const float*)d_in[2];
    const float* mu = (const float*)d_in[3];
    const float* wts = (const float*)d_in[4];
    const float* lam = (const float*)d_in[5];
    float* ws = (float*)d_ws;
    float* out = (float*)d_out;

    const bool use_ws = ws_size >= (size_t)WS_REQ;
    pre_kernel<<<1024, 256, 0, stream>>>(u, filt, mu, wts, ws, use_ws ? 1 : 0);
    dim3 grid(WW / TW, HH / TH, NBATCH);
    if (use_ws)
        tnrd_kernel<true><<<grid, NTHR, 0, stream>>>(u, f, filt, mu, wts, lam, ws, out);
    else
        tnrd_kernel<false><<<grid, NTHR, 0, stream>>>(u, f, filt, mu, wts, lam, ws, out);
}

// Round 9
// 203.434 us; speedup vs baseline: 3.5440x; 1.0377x over previous
//
#include <hip/hip_runtime.h>
#include <hip/hip_fp16.h>
#include <math.h>

#define NBATCH 8
#define HH 512
#define WW 512
#define NF 24
#define NB 31
#define TH 64
#define TW 64
#define UH 72        // TH + 8
#define UW 72        // TW + 8
#define SU_S 76      // su stride: 2-row groups shift banks {0,24,16,8}
#define UGH 68
#define UG_S 72
#define SPH 68
#define SP_WS 36     // sp row stride in u32 words (34 used); 2-row shift {0,8,16,24}
#define NTHR 512
#define SP_TASKS 578 // 34 x 17 tasks of 2 rows x 4 cols
#define LUTN 256
#define WS_LO 8
#define WS_SC 40
#define WS_LUT 72                        // u32-indexed
#define WS_PART (WS_LUT + NF * LUTN)
#define WS_REQ ((WS_PART + 1024) * 4)

__device__ __forceinline__ void phi_pair(const float* mu, const float* wts, int c,
                                         float x, float h, float* p0, float* p1) {
    float a = 0.f, b = 0.f;
    for (int j = 0; j < NB; ++j) {
        float m = mu[c * NB + j], w = wts[c * NB + j];
        float d0 = x - m, d1 = x + h - m;
        a += w * __expf(-2.f * d0 * d0);
        b += w * __expf(-2.f * d1 * d1);
    }
    *p0 = a; *p1 = b;
}

__device__ __forceinline__ void filter_range(const float* filt, int c,
                                             float* lo_, float* rng_) {
    float lo = 0.f, hi = 0.f;
    for (int i = 0; i < 25; ++i) {
        float k = filt[c * 25 + i];
        lo += fminf(k, 0.f);
        hi += fmaxf(k, 0.f);
    }
    *lo_ = lo;
    *rng_ = fmaxf(hi - lo, 1e-9f);
}

// fused pre-pass: per-block M partials (all blocks) + phi LUTs (blocks 0..23)
__global__ __launch_bounds__(256) void pre_kernel(const float* __restrict__ u,
                                                  const float* __restrict__ filt,
                                                  const float* __restrict__ mu,
                                                  const float* __restrict__ wts,
                                                  float* __restrict__ ws, int do_lut) {
    __shared__ float sred[4];
    const int tid = threadIdx.x;
    const int N = NBATCH * HH * WW;
    int stride = gridDim.x * blockDim.x;
    float s = 0.f;
    for (int i = blockIdx.x * blockDim.x + tid; i < N; i += stride) {
        int x = i & (WW - 1);
        int y = (i >> 9) & (HH - 1);
        float v = fminf(fmaxf(u[i], 1e-4f), 1.0f);
        float wy = (y == 0 || y == HH - 1) ? 2.f : 3.f;
        float wx = (x == 0 || x == WW - 1) ? 2.f : 3.f;
        s += v * (wy * wx);
    }
#pragma unroll
    for (int off = 32; off > 0; off >>= 1) s += __shfl_down(s, off, 64);
    if ((tid & 63) == 0) sred[tid >> 6] = s;
    __syncthreads();
    if (tid == 0) ws[WS_PART + blockIdx.x] = sred[0] + sred[1] + sred[2] + sred[3];

    if (do_lut && blockIdx.x < NF) {
        const int c = blockIdx.x;
        float lo, rng;
        filter_range(filt, c, &lo, &rng);
        float h = rng * (1.f / 255.f);
        float p0, p1;
        phi_pair(mu, wts, c, lo + (float)tid * h, h, &p0, &p1);
        unsigned u0 = (unsigned)__half_as_ushort(__float2half(p0));
        unsigned u1 = (unsigned)__half_as_ushort(__float2half(p1));
        ((unsigned*)ws)[WS_LUT + c * LUTN + tid] = u0 | (u1 << 16);
        if (tid == 0) { ws[WS_LO + c] = lo; ws[WS_SC + c] = 255.f / rng; }
    }
}

template <bool WSLUT>
__global__ __launch_bounds__(NTHR, 4) void tnrd_kernel(
    const float* __restrict__ u, const float* __restrict__ f,
    const float* __restrict__ filt, const float* __restrict__ mu,
    const float* __restrict__ wts, const float* __restrict__ lamp,
    const float* __restrict__ ws, float* __restrict__ out)
{
    __shared__ float su[UH][SU_S];          // clipped u, 0 outside image
    __shared__ float ug[UGH][UG_S];         // u_sigma/M, 0 outside image
    __shared__ unsigned spw[2][SPH][SP_WS]; // scaled_phi, f16x2 packed, dbuf
    __shared__ unsigned slut[2][LUTN];      // LUT dbuf
    __shared__ float sred[8];

    const int tid = threadIdx.x;
    const int bz = blockIdx.z;
    const int oy0 = blockIdx.y * TH;
    const int ox0 = blockIdx.x * TW;
    const float* ub = u + bz * HH * WW;
    const unsigned* lutg = (const unsigned*)ws + WS_LUT;

    // ---- stage clipped u tile (halo 4); zero outside image
    for (int i = tid; i < UH * UW; i += NTHR) {
        int uy = i / UW, ux = i - uy * UW;
        int gy = oy0 - 4 + uy, gx = ox0 - 4 + ux;
        float v = 0.f;
        if ((unsigned)gy < (unsigned)HH && (unsigned)gx < (unsigned)WW)
            v = fminf(fmaxf(ub[gy * WW + gx], 1e-4f), 1.0f);
        su[uy][ux] = v;
    }

    // ---- LUTs for filters 0,1
    if (WSLUT) {
        if (tid < 2 * LUTN) {
            int cc = tid >> 8, e = tid & 255;
            slut[cc][e] = lutg[cc * LUTN + e];
        }
    } else {
        for (int cc = 0; cc < 2; ++cc) {
            if (tid < LUTN) {
                float lo, rng;
                filter_range(filt, cc, &lo, &rng);
                float h = rng * (1.f / 255.f);
                float p0, p1;
                phi_pair(mu, wts, cc, lo + (float)tid * h, h, &p0, &p1);
                unsigned u0 = (unsigned)__half_as_ushort(__float2half(p0));
                unsigned u1 = (unsigned)__half_as_ushort(__float2half(p1));
                slut[cc][tid] = u0 | (u1 << 16);
            }
        }
    }

    // ---- M from partials
    {
        float ps = ws[WS_PART + tid] + ws[WS_PART + NTHR + tid];
#pragma unroll
        for (int off = 32; off > 0; off >>= 1) ps += __shfl_down(ps, off, 64);
        if ((tid & 63) == 0) sred[tid >> 6] = ps;
    }
    __syncthreads();

    float tot = 0.f;
#pragma unroll
    for (int j = 0; j < 8; ++j) tot += sred[j];
    const float Mv = tot * (1.0f / (9.0f * NBATCH * HH * WW)) + 0.001f;
    const float inv9M = (1.f / 9.f) / Mv;

    // ---- ug (u_sigma/M) over the 68x68 sp region; zero outside image
    for (int t = tid; t < SP_TASKS; t += NTHR) {
        int tr = t / 17, tc = t - tr * 17;
        int y0 = 2 * tr, x0 = 4 * tc;
        float hr[4][4];
#pragma unroll
        for (int j = 0; j < 4; ++j) {   // su rows y0+1 .. y0+4
            float4 a = *(const float4*)&su[y0 + 1 + j][x0];
            float4 b = *(const float4*)&su[y0 + 1 + j][x0 + 4];
            float t8[8] = {a.x, a.y, a.z, a.w, b.x, b.y, b.z, b.w};
#pragma unroll
            for (int k = 0; k < 4; ++k) hr[j][k] = t8[k + 1] + t8[k + 2] + t8[k + 3];
        }
#pragma unroll
        for (int r = 0; r < 2; ++r) {
            int gy = oy0 - 2 + y0 + r;
            bool ry = (unsigned)gy < (unsigned)HH;
            float o[4];
#pragma unroll
            for (int k = 0; k < 4; ++k) {
                int gx = ox0 - 2 + x0 + k;
                o[k] = (ry && (unsigned)gx < (unsigned)WW)
                         ? (hr[r][k] + hr[r + 1][k] + hr[r + 2][k]) * inv9M : 0.f;
            }
            *(float4*)&ug[y0 + r][x0] = make_float4(o[0], o[1], o[2], o[3]);
        }
    }
    __syncthreads();   // su + ug + initial LUTs ready

    // ---- helpers ----
    auto sp_phase = [&](int c, int buf) {
        const float* fc = filt + c * 25;
        float lo, scc;
        if (WSLUT) { lo = ws[WS_LO + c]; scc = ws[WS_SC + c]; }
        else { float rng; filter_range(filt, c, &lo, &rng); scc = 255.f / rng; }
        const float offc = -lo * scc;
        const unsigned* sl = &slut[buf][0];
        for (int t = tid; t < SP_TASKS; t += NTHR) {
            int tr = t / 17, tc = t - tr * 17;
            int y0 = 2 * tr, x0 = 4 * tc;
            float acc[2][4] = {{0.f}};
#pragma unroll
            for (int ky = 0; ky < 6; ++ky) {
                float4 a = *(const float4*)&su[y0 + ky][x0];
                float4 b = *(const float4*)&su[y0 + ky][x0 + 4];
                float t8[8] = {a.x, a.y, a.z, a.w, b.x, b.y, b.z, b.w};
#pragma unroll
                for (int r = 0; r < 2; ++r) {
                    int kyy = ky - r;
                    if (kyy < 0 || kyy > 4) continue;
#pragma unroll
                    for (int dx = 0; dx < 5; ++dx) {
                        float wgt = fc[kyy * 5 + dx];
#pragma unroll
                        for (int k = 0; k < 4; ++k)
                            acc[r][k] = fmaf(wgt, t8[k + dx], acc[r][k]);
                    }
                }
            }
#pragma unroll
            for (int r = 0; r < 2; ++r) {
                float4 uu = *(const float4*)&ug[y0 + r][x0];
                float uu4[4] = {uu.x, uu.y, uu.z, uu.w};
                unsigned pw[2];
#pragma unroll
                for (int half = 0; half < 2; ++half) {
                    float o0, o1;
#pragma unroll
                    for (int k2 = 0; k2 < 2; ++k2) {
                        int k = half * 2 + k2;
                        float t2 = fmaf(acc[r][k], scc, offc);
                        t2 = fminf(fmaxf(t2, 0.f), 254.999f);
                        int i0 = (int)t2;
                        float fr = t2 - (float)i0;
                        unsigned pk = sl[i0];
                        __half2 hv = *reinterpret_cast<const __half2*>(&pk);
                        float2 fv = __half22float2(hv);
                        float v = fmaf(fr, fv.y - fv.x, fv.x) * uu4[k];
                        if (k2 == 0) o0 = v; else o1 = v;
                    }
                    unsigned w0 = (unsigned)__half_as_ushort(__float2half(o0));
                    unsigned w1 = (unsigned)__half_as_ushort(__float2half(o1));
                    pw[half] = w0 | (w1 << 16);
                }
                *(uint2*)&spw[buf][y0 + r][x0 >> 1] = make_uint2(pw[0], pw[1]);
            }
        }
    };

    float dif[2][4] = {{0.f}};
    const int tr2 = tid >> 4;        // 0..31  -> out rows 2*tr2, 2*tr2+1
    const int tc2 = tid & 15;        // 0..15  -> out cols 4*tc2..+3
    const int or0 = 2 * tr2, oc0 = 4 * tc2;
    const int wrd0 = oc0 >> 1;       // even

    // ---- prologue: sp(0)
    sp_phase(0, 0);
    __syncthreads();

    // ---- main loop: ONE barrier per filter
    for (int c = 0; c < NF; ++c) {
        // prefetch LUT(c+2) into slut[c&1] (read last by sp_phase(c) one iter ago)
        unsigned nl = 0;
        const bool hp = WSLUT && (c + 2 < NF) && (tid < LUTN);
        if (hp) nl = lutg[(c + 2) * LUTN + tid];

        // sp for filter c+1 into spw[(c+1)&1] (uses slut[(c+1)&1], loaded earlier)
        if (c + 1 < NF) sp_phase(c + 1, (c + 1) & 1);

        // conv2 for filter c from spw[c&1]
        {
            const float* fc = filt + c * 25;
            const unsigned (*spc)[SP_WS] = spw[c & 1];
#pragma unroll
            for (int s = 0; s < 6; ++s) {
                uint2 a = *(const uint2*)&spc[or0 + s][wrd0];
                uint2 b = *(const uint2*)&spc[or0 + s][wrd0 + 2];
                float2 f0 = __half22float2(*reinterpret_cast<const __half2*>(&a.x));
                float2 f1 = __half22float2(*reinterpret_cast<const __half2*>(&a.y));
                float2 f2 = __half22float2(*reinterpret_cast<const __half2*>(&b.x));
                float2 f3 = __half22float2(*reinterpret_cast<const __half2*>(&b.y));
                float t8[8] = {f0.x, f0.y, f1.x, f1.y, f2.x, f2.y, f3.x, f3.y};
#pragma unroll
                for (int r = 0; r < 2; ++r) {
                    int dy = s - r;
                    if (dy < 0 || dy > 4) continue;
#pragma unroll
                    for (int dx = 0; dx < 5; ++dx) {
                        float wgt = fc[(4 - dy) * 5 + (4 - dx)];
#pragma unroll
                        for (int k = 0; k < 4; ++k)
                            dif[r][k] = fmaf(wgt, t8[k + dx], dif[r][k]);
                    }
                }
            }
        }

        // non-WSLUT fallback: compute LUT(c+2) inline
        if (!WSLUT && (c + 2 < NF) && tid < LUTN) {
            int cn = c + 2;
            float lo, rng;
            filter_range(filt, cn, &lo, &rng);
            float h = rng * (1.f / 255.f);
            float p0, p1;
            phi_pair(mu, wts, cn, lo + (float)tid * h, h, &p0, &p1);
            unsigned u0 = (unsigned)__half_as_ushort(__float2half(p0));
            unsigned u1 = (unsigned)__half_as_ushort(__float2half(p1));
            slut[c & 1][tid] = u0 | (u1 << 16);
        }
        if (hp) slut[c & 1][tid] = nl;

        if (c < NF - 1) __syncthreads();
    }

    // ---- epilogue
    {
        const float lam = lamp[0];
        const float* fb = f + bz * HH * WW;
        float* ob = out + bz * HH * WW;
#pragma unroll
        for (int r = 0; r < 2; ++r) {
            int gy = oy0 + or0 + r;
            int gx = ox0 + oc0;
            float4 uv4 = *(const float4*)&su[or0 + r + 4][oc0 + 4];
            float4 fv4 = *(const float4*)&fb[gy * WW + gx];
            float uu[4] = {uv4.x, uv4.y, uv4.z, uv4.w};
            float ff[4] = {fv4.x, fv4.y, fv4.z, fv4.w};
            float o[4];
#pragma unroll
            for (int k = 0; k < 4; ++k) {
                float uv = uu[k];
                float fv = fminf(fmaxf(ff[k], 1e-4f), 1.0f);
                float reac = lam * (uv - fv) / (uv + 0.05f);
                o[k] = fminf(fmaxf(uv - dif[r][k] - reac, 0.f), 1.f);
            }
            *(float4*)&ob[gy * WW + gx] = make_float4(o[0], o[1], o[2], o[3]);
        }
    }
}

extern "C" void kernel_launch(void* const* d_in, const int* in_sizes, int n_in,
                              void* d_out, int out_size, void* d_ws, size_t ws_size,
                              hipStream_t stream) {
    const float* u = (const float*)d_in[0];
    const float* f = (const float*)d_in[1];
    const float* filt = (const float*)d_in[2];
    const float* mu = (const float*)d_in[3];
    const float* wts = (const float*)d_in[4];
    const float* lam = (const float*)d_in[5];
    float* ws = (float*)d_ws;
    float* out = (float*)d_out;

    const bool use_ws = ws_size >= (size_t)WS_REQ;
    pre_kernel<<<1024, 256, 0, stream>>>(u, filt, mu, wts, ws, use_ws ? 1 : 0);
    dim3 grid(WW / TW, HH / TH, NBATCH);
    if (use_ws)
        tnrd_kernel<true><<<grid, NTHR, 0, stream>>>(u, f, filt, mu, wts, lam, ws, out);
    else
        tnrd_kernel<false><<<grid, NTHR, 0, stream>>>(u, f, filt, mu, wts, lam, ws, out);
}